// Round 1
// 1602.384 us; speedup vs baseline: 1.2787x; 1.2787x over previous
//
#include <hip/hip_runtime.h>
#include <hip/hip_bf16.h>

#define GLOBAL_AS __attribute__((address_space(1)))
#define LDS_AS    __attribute__((address_space(3)))

typedef __attribute__((ext_vector_type(8))) __bf16 bf16x8;
typedef __attribute__((ext_vector_type(4))) float  f32x4;

static constexpr int M = 8192;
static constexpr int N = 16384;
static constexpr int K = 4096;
static constexpr float W_EPS = 1e-6f;
#define INV_WCOUNT (1.0f / 67108864.0f)   // 1 / (16384*4096)

// ---------------------------------------------------------------- reduction
__global__ void absum_kernel(const float4* __restrict__ w, float* __restrict__ out) {
  const int total = (N * K) / 4;  // 16,777,216 float4
  int idx = blockIdx.x * blockDim.x + threadIdx.x;
  int stride = gridDim.x * blockDim.x;
  float s = 0.0f;
  for (int i = idx; i < total; i += stride) {
    float4 v = w[i];
    s += fabsf(v.x) + fabsf(v.y) + fabsf(v.z) + fabsf(v.w);
  }
  #pragma unroll
  for (int off = 32; off > 0; off >>= 1) s += __shfl_down(s, off, 64);
  __shared__ float red[4];
  const int lane = threadIdx.x & 63, wv = threadIdx.x >> 6;
  if (lane == 0) red[wv] = s;
  __syncthreads();
  if (threadIdx.x == 0) atomicAdd(out, red[0] + red[1] + red[2] + red[3]);
}

// ---------------------------------------------------------------- quantize W -> ternary bf16 {-1,0,+1}
__global__ void quant_kernel(const float4* __restrict__ w, ushort4* __restrict__ wq,
                             const float* __restrict__ wsum) {
  const float s   = fmaxf(wsum[0] * INV_WCOUNT, W_EPS);
  const float thr = 0.5f * s;
  const int total = (N * K) / 4;
  int idx = blockIdx.x * blockDim.x + threadIdx.x;
  int stride = gridDim.x * blockDim.x;
  for (int i = idx; i < total; i += stride) {
    float4 v = w[i];
    ushort4 q;
    q.x = v.x > thr ? 0x3F80u : (v.x < -thr ? 0xBF80u : 0u);
    q.y = v.y > thr ? 0x3F80u : (v.y < -thr ? 0xBF80u : 0u);
    q.z = v.z > thr ? 0x3F80u : (v.z < -thr ? 0xBF80u : 0u);
    q.w = v.w > thr ? 0x3F80u : (v.w < -thr ? 0xBF80u : 0u);
    wq[i] = q;
  }
}

// ---------------------------------------------------------------- cast x -> bf16 (RNE)
__device__ __forceinline__ unsigned short f2bf(float f) {
  unsigned int b = __float_as_uint(f);
  b += 0x7FFFu + ((b >> 16) & 1u);
  return (unsigned short)(b >> 16);
}

__global__ void castx_kernel(const float4* __restrict__ x, ushort4* __restrict__ xb) {
  const int total = (M * K) / 4;  // 8,388,608 float4
  int idx = blockIdx.x * blockDim.x + threadIdx.x;
  int stride = gridDim.x * blockDim.x;
  for (int i = idx; i < total; i += stride) {
    float4 v = x[i];
    ushort4 q;
    q.x = f2bf(v.x); q.y = f2bf(v.y); q.z = f2bf(v.z); q.w = f2bf(v.w);
    xb[i] = q;
  }
}

// ---------------------------------------------------------------- GEMM: out = (A @ B^T) * scale + bias
// 256x256 tile, BK=64, 8 waves (2M x 4N), 8-phase schedule (T2 swizzle + T3/T4
// counted vmcnt + T5 setprio). A: M x K bf16 (x), B: N x K bf16 (ternary W).
// LDS 128 KiB: A dbuf [0,64K) = 2 x (256 rows x 64 bf16), B dbuf [64K,128K).
// Swizzle: LDS[r][cb] holds global[r][cb ^ ((r&7)<<4)] (pre-swizzled global
// source, linear global_load_lds dest; same XOR applied on ds_read addresses).
#define STAGE(gp, ldsbase, tt, h) do {                                               \
    char* _l = (ldsbase) + ((tt) & 1) * 32768 + (h) * 16384 + wv * 1024;             \
    __builtin_amdgcn_global_load_lds((const GLOBAL_AS void*)(gp[h][0] + (size_t)(tt) * 64), \
                                     (LDS_AS void*)_l, 16, 0, 0);                    \
    __builtin_amdgcn_global_load_lds((const GLOBAL_AS void*)(gp[h][1] + (size_t)(tt) * 64), \
                                     (LDS_AS void*)(_l + 8192), 16, 0, 0);           \
  } while (0)

#define DSA(ih, bb) do {                                                             \
    _Pragma("unroll")                                                                \
    for (int i = 0; i < 4; ++i) {                                                    \
      Af[ih][i][0] = *(const bf16x8*)(paA0 + (bb) * 32768 + ((ih) * 64 + i * 16) * 128); \
      Af[ih][i][1] = *(const bf16x8*)(paA1 + (bb) * 32768 + ((ih) * 64 + i * 16) * 128); \
    }                                                                                \
  } while (0)

#define DSB(jh, bb) do {                                                             \
    _Pragma("unroll")                                                                \
    for (int j = 0; j < 2; ++j) {                                                    \
      Bf[jh][j][0] = *(const bf16x8*)(pbB0 + (bb) * 32768 + ((jh) * 32 + j * 16) * 128); \
      Bf[jh][j][1] = *(const bf16x8*)(pbB1 + (bb) * 32768 + ((jh) * 32 + j * 16) * 128); \
    }                                                                                \
  } while (0)

#define MFMAQ(ih, jh) do {                                                           \
    _Pragma("unroll")                                                                \
    for (int kk = 0; kk < 2; ++kk)                                                   \
      _Pragma("unroll")                                                              \
      for (int i = 0; i < 4; ++i)                                                    \
        _Pragma("unroll")                                                            \
        for (int j = 0; j < 2; ++j)                                                  \
          acc[(ih) * 4 + i][(jh) * 2 + j] = __builtin_amdgcn_mfma_f32_16x16x32_bf16( \
              Af[ih][i][kk], Bf[jh][j][kk], acc[(ih) * 4 + i][(jh) * 2 + j], 0, 0, 0); \
  } while (0)

__global__ __launch_bounds__(512, 2) void gemm_kernel(
    const __hip_bfloat16* __restrict__ A,
    const __hip_bfloat16* __restrict__ B,
    const float* __restrict__ bias,
    const float* __restrict__ wsum,
    float* __restrict__ out) {
  extern __shared__ char smem[];
  char* ldsA = smem;            // 2 x 32 KB
  char* ldsB = smem + 65536;    // 2 x 32 KB

  const int tid  = threadIdx.x;
  const int lane = tid & 63;
  const int wv   = tid >> 6;    // 0..7
  const int wm   = wv >> 2;     // 0..1 : 128 M-rows each
  const int wn   = wv & 3;      // 0..3 : 64 N-cols each
  const int tn   = blockIdx.x;  // N/256 = 64
  const int tm   = blockIdx.y;  // M/256 = 32

  // ---- staging: linear LDS dest, pre-swizzled global source column
  const int srow = tid >> 3;                                        // 0..63
  const int sce  = ((((tid & 7) << 4) ^ ((srow & 7) << 4)) >> 1);   // element col
  const __hip_bfloat16* gA[2][2];
  const __hip_bfloat16* gB[2][2];
  #pragma unroll
  for (int h = 0; h < 2; ++h)
    #pragma unroll
    for (int c = 0; c < 2; ++c) {
      gA[h][c] = A + (size_t)(tm * 256 + h * 128 + c * 64 + srow) * K + sce;
      gB[h][c] = B + (size_t)(tn * 256 + h * 128 + c * 64 + srow) * K + sce;
    }

  // ---- fragment read addressing (swizzled): row&7 == lane&7 for all frags
  const int arow = wm * 128 + (lane & 15);
  const int brow = wn * 64  + (lane & 15);
  const int xorv = (lane & 7) << 4;
  const int ac0  = (((lane >> 4) << 4) + 0)  ^ xorv;   // kk=0 column bytes
  const int ac1  = (((lane >> 4) << 4) + 64) ^ xorv;   // kk=1 column bytes
  const char* paA0 = ldsA + arow * 128 + ac0;
  const char* paA1 = ldsA + arow * 128 + ac1;
  const char* pbB0 = ldsB + brow * 128 + ac0;
  const char* pbB1 = ldsB + brow * 128 + ac1;

  const f32x4 zero = {0.f, 0.f, 0.f, 0.f};
  f32x4 acc[8][4];
  #pragma unroll
  for (int i = 0; i < 8; ++i)
    #pragma unroll
    for (int j = 0; j < 4; ++j) acc[i][j] = zero;

  bf16x8 Af[2][4][2];   // [ih][i][kk] — held in regs across phases 1..4
  bf16x8 Bf[2][2][2];   // [jh][j][kk]

  // ---- prologue: tile0 full + tile1 A-halves in flight (steady-state invariant)
  STAGE(gA, ldsA, 0, 0); STAGE(gA, ldsA, 0, 1);
  STAGE(gB, ldsB, 0, 0); STAGE(gB, ldsB, 0, 1);
  STAGE(gA, ldsA, 1, 0); STAGE(gA, ldsA, 1, 1);
  asm volatile("s_waitcnt vmcnt(4)" ::: "memory");   // tile0's 8 loads landed
  __builtin_amdgcn_s_barrier();

  for (int t = 0; t < 64; ++t) {
    const int bb = t & 1;
    // -------- phase 1: Q(0,0) — 12 ds_reads; stage (t+1,B0)
    DSA(0, bb); DSB(0, bb);
    if (t + 1 < 64) STAGE(gB, ldsB, t + 1, 0);
    __builtin_amdgcn_s_barrier();
    asm volatile("s_waitcnt lgkmcnt(0)" ::: "memory");
    __builtin_amdgcn_sched_barrier(0);
    __builtin_amdgcn_s_setprio(1);
    MFMAQ(0, 0);
    __builtin_amdgcn_s_setprio(0);
    __builtin_amdgcn_s_barrier();
    // -------- phase 2: Q(1,0) — 8 ds_reads; stage (t+1,B1)
    DSA(1, bb);
    if (t + 1 < 64) STAGE(gB, ldsB, t + 1, 1);
    __builtin_amdgcn_s_barrier();
    asm volatile("s_waitcnt lgkmcnt(0)" ::: "memory");
    __builtin_amdgcn_sched_barrier(0);
    __builtin_amdgcn_s_setprio(1);
    MFMAQ(1, 0);
    __builtin_amdgcn_s_setprio(0);
    __builtin_amdgcn_s_barrier();
    // -------- phase 3: Q(1,1) — 4 ds_reads; stage (t+2,A0)
    // (all A reads of tile t completed at end of phase 2 -> A region reusable)
    DSB(1, bb);
    if (t + 2 < 64) STAGE(gA, ldsA, t + 2, 0);
    __builtin_amdgcn_s_barrier();
    asm volatile("s_waitcnt lgkmcnt(0)" ::: "memory");
    __builtin_amdgcn_sched_barrier(0);
    __builtin_amdgcn_s_setprio(1);
    MFMAQ(1, 1);
    __builtin_amdgcn_s_setprio(0);
    __builtin_amdgcn_s_barrier();
    // -------- phase 4: Q(0,1) — 0 ds_reads (reg reuse); stage (t+2,A1)
    if (t + 2 < 64) STAGE(gA, ldsA, t + 2, 1);
    __builtin_amdgcn_s_barrier();
    __builtin_amdgcn_s_setprio(1);
    MFMAQ(0, 1);
    __builtin_amdgcn_s_setprio(0);
    // K-tile boundary: tile t+1 must be fully in LDS; leave (t+2) A-halves
    // (4 loads) in flight. Epilogue of loop drains to 0.
    if (t < 62) asm volatile("s_waitcnt vmcnt(4)" ::: "memory");
    else        asm volatile("s_waitcnt vmcnt(0)" ::: "memory");
    __builtin_amdgcn_s_barrier();
  }

  // ---- epilogue: C/D layout col = lane&15 (n), row = (lane>>4)*4 + reg (m)
  const float s  = fmaxf(wsum[0] * INV_WCOUNT, W_EPS);
  const int   n0 = tn * 256 + wn * 64 + (lane & 15);
  const int   m0 = tm * 256 + wm * 128 + ((lane >> 4) << 2);
  float bj[4];
  #pragma unroll
  for (int j = 0; j < 4; ++j) bj[j] = bias[n0 + j * 16];
  #pragma unroll
  for (int i = 0; i < 8; ++i) {
    #pragma unroll
    for (int r = 0; r < 4; ++r) {
      float* orow = out + (size_t)(m0 + i * 16 + r) * N + n0;
      #pragma unroll
      for (int j = 0; j < 4; ++j)
        orow[j * 16] = acc[i][j][r] * s + bj[j];
    }
  }
}

// ---------------------------------------------------------------- launch
extern "C" void kernel_launch(void* const* d_in, const int* in_sizes, int n_in,
                              void* d_out, int out_size, void* d_ws, size_t ws_size,
                              hipStream_t stream) {
  const float* x    = (const float*)d_in[0];   // 8192 x 4096
  const float* w    = (const float*)d_in[1];   // 16384 x 4096
  const float* bias = (const float*)d_in[2];   // 16384
  float* out = (float*)d_out;                  // 8192 x 16384

  char* ws = (char*)d_ws;
  float* wsum = (float*)ws;                                        // 4 B
  __hip_bfloat16* Wq = (__hip_bfloat16*)(ws + 256);                // 134 MB
  __hip_bfloat16* Xb = (__hip_bfloat16*)(ws + 256 + (size_t)N * K * 2);  // 67 MB

  static bool attr_set = false;
  if (!attr_set) {
    hipFuncSetAttribute((const void*)gemm_kernel,
                        hipFuncAttributeMaxDynamicSharedMemorySize, 131072);
    attr_set = true;
  }

  hipMemsetAsync(wsum, 0, sizeof(float), stream);
  absum_kernel<<<2048, 256, 0, stream>>>((const float4*)w, wsum);
  quant_kernel<<<8192, 256, 0, stream>>>((const float4*)w, (ushort4*)Wq, wsum);
  castx_kernel<<<4096, 256, 0, stream>>>((const float4*)x, (ushort4*)Xb);
  dim3 grid(N / 256, M / 256);
  gemm_kernel<<<grid, 512, 131072, stream>>>(Xb, Wq, bias, wsum, out);
}